// Round 9
// baseline (61396.564 us; speedup 1.0000x reference)
//
#include <hip/hip_runtime.h>
#include <hip/hip_cooperative_groups.h>
#include <math.h>

namespace cg = cooperative_groups;

// ---------------------------------------------------------------------------
// PointerNet rollout on MI355X — round-9: ONE persistent cooperative kernel.
// 256 blocks x 512 threads (1 block/CU), grid.sync() between phases.
// All fma chains / PRNG / sampling bit-identical to the round-8 passing kernel.
// ---------------------------------------------------------------------------

#define Bz 256
#define Sz 256
#define Ez 128
#define Hz 512
#define NEGV -1e9f
#define BH (Bz*Hz)

__device__ float g_encout[Bz*Sz*Hz];
__device__ float g_glref[Bz*Sz*Hz];
__device__ float g_ptref[Bz*Sz*Hz];
__device__ float g_xpe[256*2048];
__device__ float g_xpd[257*2048];
__device__ float g_h[2*BH];
__device__ float g_c[BH];
__device__ int g_ptrbuf[Bz];
__device__ unsigned g_keys[2*Sz];
__device__ unsigned char g_mask[Bz*Sz];

__device__ __forceinline__ unsigned rotl32(unsigned v, int d){ return (v<<d)|(v>>(32-d)); }

__device__ __forceinline__ void tf2x32(unsigned k0, unsigned k1, unsigned x0, unsigned x1,
                                       unsigned &o0, unsigned &o1){
  unsigned ks2 = k0 ^ k1 ^ 0x1BD11BDAu;
  x0 += k0; x1 += k1;
#define TFR(r) { x0 += x1; x1 = rotl32(x1,(r)); x1 ^= x0; }
  TFR(13) TFR(15) TFR(26) TFR(6)
  x0 += k1; x1 += ks2 + 1u;
  TFR(17) TFR(29) TFR(16) TFR(24)
  x0 += ks2; x1 += k0 + 2u;
  TFR(13) TFR(15) TFR(26) TFR(6)
  x0 += k0; x1 += k1 + 3u;
  TFR(17) TFR(29) TFR(16) TFR(24)
  x0 += k1; x1 += ks2 + 4u;
  TFR(13) TFR(15) TFR(26) TFR(6)
  x0 += ks2; x1 += k0 + 5u;
#undef TFR
  o0 = x0; o1 = x1;
}

__device__ __forceinline__ unsigned rng_bits(unsigned ka, unsigned kb, unsigned idx){
  unsigned o0,o1; tf2x32(ka,kb, 0u, idx, o0,o1);
  return o0 ^ o1;
}

// ---- shared-memory phase union (max = attn ~47.4 KB) ----------------------
struct AttnS {
  float hq[Hz], q2s[Hz], qgs[Hz], qps[Hz], vgl[Hz], vpt[Hz];
  float part[16][513];
  float m_arr[16], l_arr[16];
  int   rlist[16][16];
  float slog[Sz];
  float redy[8]; int redi[8]; float redm[8]; float redsum[8];
};
struct LstmS { float A[32][36]; float W[64][36]; };
struct GemmS { float As[32][68]; float Ws[32][68]; };
struct XprojS { float xs[Ez]; };
union __align__(16) SharedU { AttnS a; LstmS l; GemmS g; XprojS x; };

// ---------------------------------------------------------------------------
// LSTM phase: block = tile (bt = blk>>5, jt = blk&31); thread = 1 b x 4 gates.
// Per-accumulator k-ascending fma chain — bit-identical gates to round 8.
// ---------------------------------------------------------------------------
__device__ void lstm_phase(LstmS& S, const float* __restrict__ Whh,
                           const int* __restrict__ inputs,
                           int t, int is_dec, int hsel, int blk, int tid)
{
  const float* h_in  = g_h + (size_t)hsel*BH;
  float*       h_out = g_h + (size_t)(hsel^1)*BH;
  const float* Xp = is_dec ? g_xpd : g_xpe;

  int bt = blk >> 5, jt = blk & 31;
  int jj = tid & 15, bp = tid >> 4;      // bp 0..31
  int jglob = jt*16 + jj;
  int b = bt*32 + bp;

  int c;
  if (is_dec) c = (t == 0) ? 256 : inputs[b*Sz + g_ptrbuf[b]];
  else        c = inputs[b*Sz + t];

  float acc[4];
  {
    const float* xa = Xp + (size_t)c*2048;
    #pragma unroll
    for (int g=0; g<4; g++) acc[g] = xa[g*Hz + jglob];
  }

  int sk = (tid & 7) * 4;
  int wr = tid >> 3;                       // 0..63
  int bgA = bt*32 + (tid >> 3);            // valid when tid<256
  int wrow_g = (wr >> 4)*Hz + jt*16 + (wr & 15);

  for (int kc = 0; kc < 16; kc++){
    int k0 = kc*32;
    __syncthreads();
    if (tid < 256){
      float4 av = *(const float4*)(h_in + (size_t)bgA*Hz + k0 + sk);
      *(float4*)&S.A[tid>>3][sk] = av;
    }
    {
      const float* ws = Whh + (size_t)wrow_g*Hz + k0 + sk;
      float4 w0 = *(const float4*)ws;
      *(float4*)&S.W[wr][sk] = w0;
    }
    __syncthreads();
    #pragma unroll
    for (int k4 = 0; k4 < 8; k4++){
      float4 w0 = *(const float4*)&S.W[jj      ][k4*4];
      float4 w1 = *(const float4*)&S.W[16 + jj ][k4*4];
      float4 w2 = *(const float4*)&S.W[32 + jj ][k4*4];
      float4 w3 = *(const float4*)&S.W[48 + jj ][k4*4];
      float4 a0 = *(const float4*)&S.A[bp][k4*4];
#define LSTEP(c_) \
      acc[0]=fmaf(a0.c_,w0.c_,acc[0]); acc[1]=fmaf(a0.c_,w1.c_,acc[1]); \
      acc[2]=fmaf(a0.c_,w2.c_,acc[2]); acc[3]=fmaf(a0.c_,w3.c_,acc[3]);
      LSTEP(x) LSTEP(y) LSTEP(z) LSTEP(w)
#undef LSTEP
    }
  }

  float gi = acc[0], gf = acc[1], gg = acc[2], go = acc[3];
  float co = g_c[(size_t)b*Hz + jglob];
  float si = 1.f/(1.f + expf(-gi));
  float sf = 1.f/(1.f + expf(-gf));
  float so = 1.f/(1.f + expf(-go));
  float cn = sf*co + si*tanhf(gg);
  float hn = so*tanhf(cn);
  g_c[(size_t)b*Hz + jglob] = cn;
  h_out[(size_t)b*Hz + jglob] = hn;
  if (!is_dec) g_encout[((size_t)b*Sz + t)*Hz + jglob] = hn;
}

// ---------------------------------------------------------------------------
// gemm_ref phase: tiles 0..16383 (first 8192 -> gl_ref, rest -> pt_ref).
// 64x64 tile, thread = 4m x 2n; k-ascending chains (bit-identical outputs).
// ---------------------------------------------------------------------------
__device__ void gemm_tile(GemmS& S, const float* __restrict__ W,
                          const float* __restrict__ bias, float* __restrict__ C,
                          int mt, int nt, int tid)
{
  const float* A = g_encout;
  int tm = (tid & 15) * 4, tn = (tid >> 4) * 2;   // tn 0..62
  float acc[4][2] = {};
  int lr = tid >> 3;            // 0..63
  int lk = (tid & 7) * 4;       // 0..28

  for (int kc = 0; kc < 16; kc++){
    int k0 = kc*32;
    __syncthreads();
    {
      const float* ar = A + (size_t)(mt + lr)*Hz + k0 + lk;
      float4 a0 = *(const float4*)ar;
      S.As[lk+0][lr]=a0.x; S.As[lk+1][lr]=a0.y; S.As[lk+2][lr]=a0.z; S.As[lk+3][lr]=a0.w;
      const float* wrp = W + (size_t)(nt + lr)*Hz + k0 + lk;
      float4 w0 = *(const float4*)wrp;
      S.Ws[lk+0][lr]=w0.x; S.Ws[lk+1][lr]=w0.y; S.Ws[lk+2][lr]=w0.z; S.Ws[lk+3][lr]=w0.w;
    }
    __syncthreads();
    #pragma unroll
    for (int k=0;k<32;k++){
      float4 av = *(const float4*)&S.As[k][tm];
      float2 wv = *(const float2*)&S.Ws[k][tn];
      acc[0][0]=fmaf(av.x,wv.x,acc[0][0]); acc[0][1]=fmaf(av.x,wv.y,acc[0][1]);
      acc[1][0]=fmaf(av.y,wv.x,acc[1][0]); acc[1][1]=fmaf(av.y,wv.y,acc[1][1]);
      acc[2][0]=fmaf(av.z,wv.x,acc[2][0]); acc[2][1]=fmaf(av.z,wv.y,acc[2][1]);
      acc[3][0]=fmaf(av.w,wv.x,acc[3][0]); acc[3][1]=fmaf(av.w,wv.y,acc[3][1]);
    }
  }
  float b0v = bias[nt+tn+0], b1v = bias[nt+tn+1];
  #pragma unroll
  for (int i=0;i<4;i++){
    float2 o; o.x = acc[i][0] + b0v; o.y = acc[i][1] + b1v;
    *(float2*)(C + (size_t)(mt + tm + i)*Hz + nt + tn) = o;
  }
}

// ---------------------------------------------------------------------------
// attn phase: round-8 attn_step body verbatim (b = blk), shared via union.
// ---------------------------------------------------------------------------
__device__ void attn_phase(AttnS& S,
    const float* __restrict__ gl_Wq, const float* __restrict__ gl_bq,
    const float* __restrict__ gl_V,
    const float* __restrict__ pt_Wq, const float* __restrict__ pt_bq,
    const float* __restrict__ pt_V,
    int t, int hsel2, float* __restrict__ out, int b, int tid)
{
  int wave = tid >> 6, lane64 = tid & 63;
  int g = tid >> 5, lane = tid & 31;

  S.hq[tid]  = g_h[(size_t)hsel2*BH + (size_t)b*Hz + tid];
  S.vgl[tid] = gl_V[tid];
  S.vpt[tid] = pt_V[tid];
  __syncthreads();

  const unsigned char* mrow = g_mask + b*Sz;

  // ---- compacted row list per group
  int cnt;
  {
    bool un = (lane < 16) ? (mrow[g*16 + lane] == 0) : false;
    unsigned long long bal = __ballot(un);
    unsigned m16 = (unsigned)((g & 1) ? (bal >> 32) : bal) & 0xFFFFu;
    cnt = __popc(m16);
    if (lane < 16){
      if (un){
        int rank = __popc(m16 & ((1u << lane) - 1u));
        S.rlist[g][rank] = g*16 + lane;
      } else {
        S.slog[g*16 + lane] = NEGV;
      }
    }
  }

  // ---- q2 = gl_Wq @ h + gl_bq (unroll 2)
  {
    float hv[8];
    #pragma unroll
    for (int i=0;i<8;i++) hv[i] = S.hq[lane64*8 + i];
    for (int jj=0;jj<64;jj+=2){
      int j0 = wave*64 + jj;
      const float* wr0 = gl_Wq + (size_t)j0*Hz + lane64*8;
      const float* wr1 = wr0 + Hz;
      float4 A0 = *(const float4*)wr0, A1 = *(const float4*)(wr0+4);
      float4 B0 = *(const float4*)wr1, B1 = *(const float4*)(wr1+4);
      float p0 = 0.f, p1 = 0.f;
      p0 = fmaf(hv[0], A0.x, p0); p0 = fmaf(hv[1], A0.y, p0);
      p0 = fmaf(hv[2], A0.z, p0); p0 = fmaf(hv[3], A0.w, p0);
      p0 = fmaf(hv[4], A1.x, p0); p0 = fmaf(hv[5], A1.y, p0);
      p0 = fmaf(hv[6], A1.z, p0); p0 = fmaf(hv[7], A1.w, p0);
      p1 = fmaf(hv[0], B0.x, p1); p1 = fmaf(hv[1], B0.y, p1);
      p1 = fmaf(hv[2], B0.z, p1); p1 = fmaf(hv[3], B0.w, p1);
      p1 = fmaf(hv[4], B1.x, p1); p1 = fmaf(hv[5], B1.y, p1);
      p1 = fmaf(hv[6], B1.z, p1); p1 = fmaf(hv[7], B1.w, p1);
      #pragma unroll
      for (int off=32; off; off>>=1) p0 += __shfl_xor(p0, off);
      #pragma unroll
      for (int off=32; off; off>>=1) p1 += __shfl_xor(p1, off);
      if (lane64 == 0){ S.q2s[j0] = p0 + gl_bq[j0]; S.q2s[j0+1] = p1 + gl_bq[j0+1]; }
    }
  }
  __syncthreads();

  // ---- glimpse: online softmax over compacted rows, depth-1 prefetch
  const float* glbase = g_glref + (size_t)b*Sz*Hz;
  {
    float m_g = -INFINITY, l_g = 0.f;
    float4 racc[4];
    { float4 z = {0.f,0.f,0.f,0.f}; racc[0]=z; racc[1]=z; racc[2]=z; racc[3]=z; }

    float4 xn0, xn1, xn2, xn3;
    if (cnt > 0){
      const float4* rp = (const float4*)(glbase + (size_t)S.rlist[g][0]*Hz);
      xn0 = rp[lane]; xn1 = rp[lane+32]; xn2 = rp[lane+64]; xn3 = rp[lane+96];
    }
    for (int i = 0; i < cnt; i++){
      float4 x0 = xn0, x1 = xn1, x2 = xn2, x3 = xn3;
      if (i + 1 < cnt){
        const float4* rp = (const float4*)(glbase + (size_t)S.rlist[g][i+1]*Hz);
        xn0 = rp[lane]; xn1 = rp[lane+32]; xn2 = rp[lane+64]; xn3 = rp[lane+96];
      }
      float p = 0.f;
      {
        float4 q, vv;
        q = *(const float4*)&S.q2s[lane*4];        vv = *(const float4*)&S.vgl[lane*4];
        p = fmaf(vv.x, tanhf(q.x + x0.x), p); p = fmaf(vv.y, tanhf(q.y + x0.y), p);
        p = fmaf(vv.z, tanhf(q.z + x0.z), p); p = fmaf(vv.w, tanhf(q.w + x0.w), p);
        q = *(const float4*)&S.q2s[(lane+32)*4];   vv = *(const float4*)&S.vgl[(lane+32)*4];
        p = fmaf(vv.x, tanhf(q.x + x1.x), p); p = fmaf(vv.y, tanhf(q.y + x1.y), p);
        p = fmaf(vv.z, tanhf(q.z + x1.z), p); p = fmaf(vv.w, tanhf(q.w + x1.w), p);
        q = *(const float4*)&S.q2s[(lane+64)*4];   vv = *(const float4*)&S.vgl[(lane+64)*4];
        p = fmaf(vv.x, tanhf(q.x + x2.x), p); p = fmaf(vv.y, tanhf(q.y + x2.y), p);
        p = fmaf(vv.z, tanhf(q.z + x2.z), p); p = fmaf(vv.w, tanhf(q.w + x2.w), p);
        q = *(const float4*)&S.q2s[(lane+96)*4];   vv = *(const float4*)&S.vgl[(lane+96)*4];
        p = fmaf(vv.x, tanhf(q.x + x3.x), p); p = fmaf(vv.y, tanhf(q.y + x3.y), p);
        p = fmaf(vv.z, tanhf(q.z + x3.z), p); p = fmaf(vv.w, tanhf(q.w + x3.w), p);
      }
      #pragma unroll
      for (int off=16; off; off>>=1) p += __shfl_xor(p, off, 32);
      float lgv = p;
      if (lgv > m_g){
        float r_ = expf(m_g - lgv);
        l_g *= r_;
        racc[0].x*=r_; racc[0].y*=r_; racc[0].z*=r_; racc[0].w*=r_;
        racc[1].x*=r_; racc[1].y*=r_; racc[1].z*=r_; racc[1].w*=r_;
        racc[2].x*=r_; racc[2].y*=r_; racc[2].z*=r_; racc[2].w*=r_;
        racc[3].x*=r_; racc[3].y*=r_; racc[3].z*=r_; racc[3].w*=r_;
        m_g = lgv;
      }
      float pr = expf(lgv - m_g);
      l_g += pr;
      racc[0].x=fmaf(pr,x0.x,racc[0].x); racc[0].y=fmaf(pr,x0.y,racc[0].y);
      racc[0].z=fmaf(pr,x0.z,racc[0].z); racc[0].w=fmaf(pr,x0.w,racc[0].w);
      racc[1].x=fmaf(pr,x1.x,racc[1].x); racc[1].y=fmaf(pr,x1.y,racc[1].y);
      racc[1].z=fmaf(pr,x1.z,racc[1].z); racc[1].w=fmaf(pr,x1.w,racc[1].w);
      racc[2].x=fmaf(pr,x2.x,racc[2].x); racc[2].y=fmaf(pr,x2.y,racc[2].y);
      racc[2].z=fmaf(pr,x2.z,racc[2].z); racc[2].w=fmaf(pr,x2.w,racc[2].w);
      racc[3].x=fmaf(pr,x3.x,racc[3].x); racc[3].y=fmaf(pr,x3.y,racc[3].y);
      racc[3].z=fmaf(pr,x3.z,racc[3].z); racc[3].w=fmaf(pr,x3.w,racc[3].w);
    }
    if (lane == 0){ S.m_arr[g] = m_g; S.l_arr[g] = l_g; }
    S.part[g][4*lane+  0] = racc[0].x; S.part[g][4*lane+  1] = racc[0].y;
    S.part[g][4*lane+  2] = racc[0].z; S.part[g][4*lane+  3] = racc[0].w;
    S.part[g][4*lane+128] = racc[1].x; S.part[g][4*lane+129] = racc[1].y;
    S.part[g][4*lane+130] = racc[1].z; S.part[g][4*lane+131] = racc[1].w;
    S.part[g][4*lane+256] = racc[2].x; S.part[g][4*lane+257] = racc[2].y;
    S.part[g][4*lane+258] = racc[2].z; S.part[g][4*lane+259] = racc[2].w;
    S.part[g][4*lane+384] = racc[3].x; S.part[g][4*lane+385] = racc[3].y;
    S.part[g][4*lane+386] = racc[3].z; S.part[g][4*lane+387] = racc[3].w;
  }
  __syncthreads();

  // ---- merge group partials -> qg
  {
    float M = S.m_arr[0];
    #pragma unroll
    for (int gg=1; gg<16; gg++) M = fmaxf(M, S.m_arr[gg]);
    float num = 0.f, den = 0.f;
    #pragma unroll
    for (int gg=0; gg<16; gg++){
      float w = expf(S.m_arr[gg] - M);
      num = fmaf(w, S.part[gg][tid], num);
      den = fmaf(w, S.l_arr[gg], den);
    }
    S.qgs[tid] = num / den;
  }
  __syncthreads();

  // ---- qpt = pt_Wq @ qg + pt_bq (unroll 2)
  {
    float qv[8];
    #pragma unroll
    for (int i=0;i<8;i++) qv[i] = S.qgs[lane64*8 + i];
    for (int jj=0;jj<64;jj+=2){
      int j0 = wave*64 + jj;
      const float* wr0 = pt_Wq + (size_t)j0*Hz + lane64*8;
      const float* wr1 = wr0 + Hz;
      float4 A0 = *(const float4*)wr0, A1 = *(const float4*)(wr0+4);
      float4 B0 = *(const float4*)wr1, B1 = *(const float4*)(wr1+4);
      float p0 = 0.f, p1 = 0.f;
      p0 = fmaf(qv[0], A0.x, p0); p0 = fmaf(qv[1], A0.y, p0);
      p0 = fmaf(qv[2], A0.z, p0); p0 = fmaf(qv[3], A0.w, p0);
      p0 = fmaf(qv[4], A1.x, p0); p0 = fmaf(qv[5], A1.y, p0);
      p0 = fmaf(qv[6], A1.z, p0); p0 = fmaf(qv[7], A1.w, p0);
      p1 = fmaf(qv[0], B0.x, p1); p1 = fmaf(qv[1], B0.y, p1);
      p1 = fmaf(qv[2], B0.z, p1); p1 = fmaf(qv[3], B0.w, p1);
      p1 = fmaf(qv[4], B1.x, p1); p1 = fmaf(qv[5], B1.y, p1);
      p1 = fmaf(qv[6], B1.z, p1); p1 = fmaf(qv[7], B1.w, p1);
      #pragma unroll
      for (int off=32; off; off>>=1) p0 += __shfl_xor(p0, off);
      #pragma unroll
      for (int off=32; off; off>>=1) p1 += __shfl_xor(p1, off);
      if (lane64 == 0){ S.qps[j0] = p0 + pt_bq[j0]; S.qps[j0+1] = p1 + pt_bq[j0+1]; }
    }
  }
  __syncthreads();

  // ---- pointer pass: compacted rows, depth-1 prefetch
  const float* ptbase = g_ptref + (size_t)b*Sz*Hz;
  {
    float4 xn0, xn1, xn2, xn3;
    if (cnt > 0){
      const float4* rp = (const float4*)(ptbase + (size_t)S.rlist[g][0]*Hz);
      xn0 = rp[lane]; xn1 = rp[lane+32]; xn2 = rp[lane+64]; xn3 = rp[lane+96];
    }
    for (int i = 0; i < cnt; i++){
      int s = S.rlist[g][i];
      float4 x0 = xn0, x1 = xn1, x2 = xn2, x3 = xn3;
      if (i + 1 < cnt){
        const float4* rp = (const float4*)(ptbase + (size_t)S.rlist[g][i+1]*Hz);
        xn0 = rp[lane]; xn1 = rp[lane+32]; xn2 = rp[lane+64]; xn3 = rp[lane+96];
      }
      float p = 0.f;
      {
        float4 q, vv;
        q = *(const float4*)&S.qps[lane*4];        vv = *(const float4*)&S.vpt[lane*4];
        p = fmaf(vv.x, tanhf(q.x + x0.x), p); p = fmaf(vv.y, tanhf(q.y + x0.y), p);
        p = fmaf(vv.z, tanhf(q.z + x0.z), p); p = fmaf(vv.w, tanhf(q.w + x0.w), p);
        q = *(const float4*)&S.qps[(lane+32)*4];   vv = *(const float4*)&S.vpt[(lane+32)*4];
        p = fmaf(vv.x, tanhf(q.x + x1.x), p); p = fmaf(vv.y, tanhf(q.y + x1.y), p);
        p = fmaf(vv.z, tanhf(q.z + x1.z), p); p = fmaf(vv.w, tanhf(q.w + x1.w), p);
        q = *(const float4*)&S.qps[(lane+64)*4];   vv = *(const float4*)&S.vpt[(lane+64)*4];
        p = fmaf(vv.x, tanhf(q.x + x2.x), p); p = fmaf(vv.y, tanhf(q.y + x2.y), p);
        p = fmaf(vv.z, tanhf(q.z + x2.z), p); p = fmaf(vv.w, tanhf(q.w + x2.w), p);
        q = *(const float4*)&S.qps[(lane+96)*4];   vv = *(const float4*)&S.vpt[(lane+96)*4];
        p = fmaf(vv.x, tanhf(q.x + x3.x), p); p = fmaf(vv.y, tanhf(q.y + x3.y), p);
        p = fmaf(vv.z, tanhf(q.z + x3.z), p); p = fmaf(vv.w, tanhf(q.w + x3.w), p);
      }
      #pragma unroll
      for (int off=16; off; off>>=1) p += __shfl_xor(p, off, 32);
      if (lane == 0) S.slog[s] = 10.f * tanhf(p);
    }
  }
  __syncthreads();

  // ---- Gumbel-max sample
  float lg = NEGV, y = -INFINITY;
  if (tid < Sz){
    lg = S.slog[tid];
    unsigned bits = rng_bits(g_keys[2*t], g_keys[2*t+1], (unsigned)(b*Sz + tid));
    float u = __uint_as_float((bits >> 9) | 0x3f800000u) - 1.f;
    float gum = -logf(-logf(u + 1e-10f) + 1e-10f);
    y = lg + gum;
  }
  float by = y; int bi = tid; float bm = lg;
  #pragma unroll
  for (int off=32; off; off>>=1){
    float oy = __shfl_xor(by, off);
    int   oi = __shfl_xor(bi, off);
    float om = __shfl_xor(bm, off);
    if (oy > by || (oy == by && oi < bi)){ by = oy; bi = oi; }
    bm = fmaxf(bm, om);
  }
  if (lane64 == 0){ S.redy[wave] = by; S.redi[wave] = bi; S.redm[wave] = bm; }
  __syncthreads();
  float fy = S.redy[0]; int fi = S.redi[0]; float fm = S.redm[0];
  #pragma unroll
  for (int w=1; w<8; w++){
    if (S.redy[w] > fy || (S.redy[w] == fy && S.redi[w] < fi)){ fy = S.redy[w]; fi = S.redi[w]; }
    fm = fmaxf(fm, S.redm[w]);
  }
  int ptr = fi;

  float pe = (tid < Sz) ? expf(lg - fm) : 0.f;
  #pragma unroll
  for (int off=32; off; off>>=1) pe += __shfl_xor(pe, off);
  if (lane64 == 0) S.redsum[wave] = pe;
  __syncthreads();
  if (tid == 0){
    float den = ((S.redsum[0]+S.redsum[1]) + (S.redsum[2]+S.redsum[3]))
              + ((S.redsum[4]+S.redsum[5]) + (S.redsum[6]+S.redsum[7]));
    float logp = S.slog[ptr] - fm - logf(den);
    out[(size_t)b*Sz + t] = (float)ptr;
    out[(size_t)Bz*Sz + (size_t)b*Sz + t] = logp;
    g_mask[b*Sz + ptr] = 1;
    g_ptrbuf[b] = ptr;
  }
}

// ---------------------------------------------------------------------------
// The one persistent kernel.
// ---------------------------------------------------------------------------
__global__ void __launch_bounds__(512)
rollout_kernel(const float* embedding, const float* enc_Wih, const float* enc_Whh,
  const float* enc_b, const float* dec_Wih, const float* dec_Whh, const float* dec_b,
  const float* pt_Wq, const float* pt_bq, const float* pt_Wref, const float* pt_bref,
  const float* pt_V, const float* gl_Wq, const float* gl_bq, const float* gl_Wref,
  const float* gl_bref, const float* gl_V, const float* dec_start, const int* inputs,
  float* out)
{
  cg::grid_group grid = cg::this_grid();
  __shared__ SharedU sh;
  int blk = blockIdx.x, tid = threadIdx.x;

  // ---- init (covers exactly BH = 256*512 threads)
  {
    int i = blk*512 + tid;
    if (i < BH){ g_h[i] = 0.f; g_c[i] = 0.f; }
    if (i < Bz*Sz) g_mask[i] = 0;
    if (i < Sz){
      unsigned o0,o1; tf2x32(0u,1u, 0u, (unsigned)i, o0,o1);
      g_keys[2*i] = o0; g_keys[2*i+1] = o1;
    }
  }

  // ---- xproj: 2052 tiles of (c, 512-row chunk); k-ascending from bias
  for (int tile = blk; tile < 2052; tile += 256){
    int is_dec = tile >= 1024;
    int idx = is_dec ? tile - 1024 : tile;
    int c = idx >> 2, chunk = idx & 3;
    const float* Wih  = is_dec ? dec_Wih : enc_Wih;
    const float* bias = is_dec ? dec_b   : enc_b;
    float* Xp = is_dec ? g_xpd : g_xpe;
    __syncthreads();
    if (tid < Ez) sh.x.xs[tid] = (c < 256) ? embedding[c*Ez + tid] : dec_start[tid];
    __syncthreads();
    int row = chunk*512 + tid;
    float a = bias[row];
    const float* w = Wih + (size_t)row*Ez;
    #pragma unroll 8
    for (int k = 0; k < Ez; k++) a = fmaf(sh.x.xs[k], w[k], a);
    Xp[(size_t)c*2048 + row] = a;
  }
  grid.sync();

  // ---- encoder: 256 sync'd lstm steps
  for (int t = 0; t < Sz; t++){
    lstm_phase(sh.l, enc_Whh, inputs, t, 0, t & 1, blk, tid);
    grid.sync();
  }

  // ---- ref projections: 16384 tiles over 256 blocks (64 each)
  for (int tile = blk; tile < 16384; tile += 256){
    int sel = tile >> 13;                  // 0: gl, 1: pt
    int mt = ((tile & 8191) >> 3) * 64;
    int nt = (tile & 7) * 64;
    if (sel == 0) gemm_tile(sh.g, gl_Wref, gl_bref, g_glref, mt, nt, tid);
    else          gemm_tile(sh.g, pt_Wref, pt_bref, g_ptref, mt, nt, tid);
  }
  grid.sync();

  // ---- decoder: lstm phase -> sync -> attn phase -> sync
  for (int t = 0; t < Sz; t++){
    lstm_phase(sh.l, dec_Whh, inputs, t, 1, t & 1, blk, tid);
    grid.sync();
    attn_phase(sh.a, gl_Wq, gl_bq, gl_V, pt_Wq, pt_bq, pt_V,
               t, (t+1) & 1, out, blk, tid);
    grid.sync();
  }
}

// ---------------------------------------------------------------------------
extern "C" void kernel_launch(void* const* d_in, const int* in_sizes, int n_in,
                              void* d_out, int out_size, void* d_ws, size_t ws_size,
                              hipStream_t stream){
  (void)in_sizes; (void)n_in; (void)out_size; (void)d_ws; (void)ws_size;
  const float* embedding = (const float*)d_in[0];
  const float* enc_Wih = (const float*)d_in[1];
  const float* enc_Whh = (const float*)d_in[2];
  const float* enc_b   = (const float*)d_in[3];
  const float* dec_Wih = (const float*)d_in[4];
  const float* dec_Whh = (const float*)d_in[5];
  const float* dec_b   = (const float*)d_in[6];
  const float* pt_Wq   = (const float*)d_in[7];
  const float* pt_bq   = (const float*)d_in[8];
  const float* pt_Wref = (const float*)d_in[9];
  const float* pt_bref = (const float*)d_in[10];
  const float* pt_V    = (const float*)d_in[11];
  const float* gl_Wq   = (const float*)d_in[12];
  const float* gl_bq   = (const float*)d_in[13];
  const float* gl_Wref = (const float*)d_in[14];
  const float* gl_bref = (const float*)d_in[15];
  const float* gl_V    = (const float*)d_in[16];
  const float* dec_start = (const float*)d_in[17];
  const int*   inputs  = (const int*)d_in[18];
  float* out = (float*)d_out;

  void* args[] = {
    (void*)&embedding, (void*)&enc_Wih, (void*)&enc_Whh, (void*)&enc_b,
    (void*)&dec_Wih, (void*)&dec_Whh, (void*)&dec_b,
    (void*)&pt_Wq, (void*)&pt_bq, (void*)&pt_Wref, (void*)&pt_bref, (void*)&pt_V,
    (void*)&gl_Wq, (void*)&gl_bq, (void*)&gl_Wref, (void*)&gl_bref, (void*)&gl_V,
    (void*)&dec_start, (void*)&inputs, (void*)&out
  };
  hipLaunchCooperativeKernel((void*)rollout_kernel, dim3(256), dim3(512),
                             args, 0, stream);
}

// Round 10
// 37521.265 us; speedup vs baseline: 1.6363x; 1.6363x over previous
//
#include <hip/hip_runtime.h>
#include <math.h>

// ---------------------------------------------------------------------------
// PointerNet rollout on MI355X — round-10.
// r8 multi-kernel structure (grid.sync costs ~35µs/sync on 8 XCDs — measured
// r9). attn: q/V hoisted to regs (kills 4-way LDS conflicts: 1.5e9 cycles in
// r9 PMC), 2-row pairing for ILP. lstm: 512 blocks (2/CU). All fma chains,
// PRNG, sampling bit-identical to the r8 passing kernel.
// ---------------------------------------------------------------------------

#define Bz 256
#define Sz 256
#define Ez 128
#define Hz 512
#define NEGV -1e9f
#define BH (Bz*Hz)

__device__ float g_encout[Bz*Sz*Hz];
__device__ float g_glref[Bz*Sz*Hz];
__device__ float g_ptref[Bz*Sz*Hz];
__device__ float g_xpe[256*2048];
__device__ float g_xpd[257*2048];
__device__ float g_h[2*BH];
__device__ float g_c[BH];
__device__ int g_ptrbuf[Bz];
__device__ unsigned g_keys[2*Sz];
__device__ unsigned char g_mask[Bz*Sz];

__device__ __forceinline__ unsigned rotl32(unsigned v, int d){ return (v<<d)|(v>>(32-d)); }

__device__ __forceinline__ void tf2x32(unsigned k0, unsigned k1, unsigned x0, unsigned x1,
                                       unsigned &o0, unsigned &o1){
  unsigned ks2 = k0 ^ k1 ^ 0x1BD11BDAu;
  x0 += k0; x1 += k1;
#define TFR(r) { x0 += x1; x1 = rotl32(x1,(r)); x1 ^= x0; }
  TFR(13) TFR(15) TFR(26) TFR(6)
  x0 += k1; x1 += ks2 + 1u;
  TFR(17) TFR(29) TFR(16) TFR(24)
  x0 += ks2; x1 += k0 + 2u;
  TFR(13) TFR(15) TFR(26) TFR(6)
  x0 += k0; x1 += k1 + 3u;
  TFR(17) TFR(29) TFR(16) TFR(24)
  x0 += k1; x1 += ks2 + 4u;
  TFR(13) TFR(15) TFR(26) TFR(6)
  x0 += ks2; x1 += k0 + 5u;
#undef TFR
  o0 = x0; o1 = x1;
}

__device__ __forceinline__ unsigned rng_bits(unsigned ka, unsigned kb, unsigned idx){
  unsigned o0,o1; tf2x32(ka,kb, 0u, idx, o0,o1);
  return o0 ^ o1;
}

// ---------------------------------------------------------------------------
__global__ __launch_bounds__(256) void init_kernel(){
  int i = blockIdx.x*256 + threadIdx.x;
  if (i < BH){ g_h[i] = 0.f; g_c[i] = 0.f; }
  if (i < Bz*Sz) g_mask[i] = 0;
  if (i < Sz){
    unsigned o0,o1; tf2x32(0u,1u, 0u, (unsigned)i, o0,o1);
    g_keys[2*i] = o0; g_keys[2*i+1] = o1;
  }
}

// ---------------------------------------------------------------------------
// Xp[c][row] = bias[row] + sum_k emb[c][k]*Wih[row][k] (k ascending from bias).
// ---------------------------------------------------------------------------
__global__ __launch_bounds__(256) void xproj_kernel(
    const float* __restrict__ Wih, const float* __restrict__ bias,
    const float* __restrict__ emb, const float* __restrict__ dstart,
    int dst)
{
  float* Xp = dst ? g_xpd : g_xpe;
  int c = blockIdx.x;
  int row = blockIdx.y*256 + threadIdx.x;
  __shared__ float xs[Ez];
  if (threadIdx.x < Ez) xs[threadIdx.x] = (c < 256) ? emb[c*Ez + threadIdx.x]
                                                    : dstart[threadIdx.x];
  __syncthreads();
  float a = bias[row];
  const float* w = Wih + (size_t)row*Ez;
  #pragma unroll 8
  for (int k = 0; k < Ez; k++) a = fmaf(xs[k], w[k], a);
  Xp[(size_t)c*2048 + row] = a;
}

// ---------------------------------------------------------------------------
// LSTM step v5: gates = Xp[city] + h@Whh^T (K=512), k-ascending chains.
// grid (16,32) = 512 blocks (2/CU), 256 thr; block = 16 b x 64 gate-rows;
// thread = 1 b x 4 gates. Bit-identical gates to r8 (same per-acc chain).
// ---------------------------------------------------------------------------
__global__ __launch_bounds__(256) void lstm_step(
    const float* __restrict__ Whh,   // [2048][512]
    const int*   __restrict__ inputs,// [Bz][Sz]
    int t, int is_dec, int hsel)
{
  __shared__ float A_lds[16][36];   // [b][k]
  __shared__ float W_lds[64][36];   // [row][k], row = gate*16 + jj

  const float* h_in = g_h + (size_t)hsel*BH;
  float*       h_out = g_h + (size_t)(hsel^1)*BH;
  const float* Xp = is_dec ? g_xpd : g_xpe;

  int tid = threadIdx.x;
  int bt = blockIdx.x;     // 0..15 (16 b)
  int jt = blockIdx.y;     // 0..31 (16 j)
  int jj = tid & 15;
  int bp = tid >> 4;       // 0..15 (1 b)
  int jglob = jt*16 + jj;
  int b = bt*16 + bp;

  int c;
  if (is_dec) c = (t == 0) ? 256 : inputs[b*Sz + g_ptrbuf[b]];
  else        c = inputs[b*Sz + t];

  float acc[4];
  {
    const float* xa = Xp + (size_t)c*2048;
    #pragma unroll
    for (int g=0; g<4; g++) acc[g] = xa[g*Hz + jglob];
  }

  // staging indices
  int ar = tid >> 3;          // 0..31 (A rows 0..15 use tid<128)
  int ak = (tid & 7) * 4;
  int wr = tid >> 2;          // 0..63
  int wk = (tid & 3) * 8;
  int wrow_g = (wr >> 4)*Hz + jt*16 + (wr & 15);

  for (int kc = 0; kc < 16; kc++){
    int k0 = kc*32;
    __syncthreads();
    if (tid < 128){
      float4 av = *(const float4*)(h_in + (size_t)(bt*16 + ar)*Hz + k0 + ak);
      *(float4*)&A_lds[ar][ak] = av;
    }
    {
      const float* ws = Whh + (size_t)wrow_g*Hz + k0 + wk;
      float4 w0 = *(const float4*)ws;
      float4 w1 = *(const float4*)(ws + 4);
      *(float4*)&W_lds[wr][wk]     = w0;
      *(float4*)&W_lds[wr][wk + 4] = w1;
    }
    __syncthreads();
    #pragma unroll
    for (int k4 = 0; k4 < 8; k4++){
      float4 w0 = *(const float4*)&W_lds[jj      ][k4*4];
      float4 w1 = *(const float4*)&W_lds[16 + jj ][k4*4];
      float4 w2 = *(const float4*)&W_lds[32 + jj ][k4*4];
      float4 w3 = *(const float4*)&W_lds[48 + jj ][k4*4];
      float4 a0 = *(const float4*)&A_lds[bp][k4*4];
#define LSTEP(c_) \
      acc[0]=fmaf(a0.c_,w0.c_,acc[0]); acc[1]=fmaf(a0.c_,w1.c_,acc[1]); \
      acc[2]=fmaf(a0.c_,w2.c_,acc[2]); acc[3]=fmaf(a0.c_,w3.c_,acc[3]);
      LSTEP(x) LSTEP(y) LSTEP(z) LSTEP(w)
#undef LSTEP
    }
  }

  float gi = acc[0], gf = acc[1], gg = acc[2], go = acc[3];
  float co = g_c[(size_t)b*Hz + jglob];
  float si = 1.f/(1.f + expf(-gi));
  float sf = 1.f/(1.f + expf(-gf));
  float so = 1.f/(1.f + expf(-go));
  float cn = sf*co + si*tanhf(gg);
  float hn = so*tanhf(cn);
  g_c[(size_t)b*Hz + jglob] = cn;
  h_out[(size_t)b*Hz + jglob] = hn;
  if (!is_dec) g_encout[((size_t)b*Sz + t)*Hz + jglob] = hn;
}

// ---------------------------------------------------------------------------
// ref projections: C[65536][512] = enc_out @ W^T + b. 64x64 tile (r8 verbatim).
// ---------------------------------------------------------------------------
__global__ __launch_bounds__(256) void gemm_ref(
    const float* __restrict__ W, const float* __restrict__ bias, int dst_id)
{
  const float* A = g_encout;
  float*       C = (dst_id == 1) ? g_glref : g_ptref;
  __shared__ float As[32][68];
  __shared__ float Ws[32][68];
  int tid = threadIdx.x;
  int mt = blockIdx.x * 64, nt = blockIdx.y * 64;
  int tm = (tid & 15) * 4, tn = (tid >> 4) * 4;
  float acc[4][4] = {};
  int lr = tid >> 2;
  int lk = (tid & 3) * 8;

  for (int kc = 0; kc < 16; kc++){
    int k0 = kc*32;
    __syncthreads();
    {
      const float* ar = A + (size_t)(mt + lr)*Hz + k0 + lk;
      float4 a0 = *(const float4*)ar, a1 = *(const float4*)(ar+4);
      As[lk+0][lr]=a0.x; As[lk+1][lr]=a0.y; As[lk+2][lr]=a0.z; As[lk+3][lr]=a0.w;
      As[lk+4][lr]=a1.x; As[lk+5][lr]=a1.y; As[lk+6][lr]=a1.z; As[lk+7][lr]=a1.w;
      const float* wrp = W + (size_t)(nt + lr)*Hz + k0 + lk;
      float4 w0 = *(const float4*)wrp, w1 = *(const float4*)(wrp+4);
      Ws[lk+0][lr]=w0.x; Ws[lk+1][lr]=w0.y; Ws[lk+2][lr]=w0.z; Ws[lk+3][lr]=w0.w;
      Ws[lk+4][lr]=w1.x; Ws[lk+5][lr]=w1.y; Ws[lk+6][lr]=w1.z; Ws[lk+7][lr]=w1.w;
    }
    __syncthreads();
    #pragma unroll
    for (int k=0;k<32;k++){
      float4 av = *(const float4*)&As[k][tm];
      float4 wv = *(const float4*)&Ws[k][tn];
      acc[0][0]=fmaf(av.x,wv.x,acc[0][0]); acc[0][1]=fmaf(av.x,wv.y,acc[0][1]);
      acc[0][2]=fmaf(av.x,wv.z,acc[0][2]); acc[0][3]=fmaf(av.x,wv.w,acc[0][3]);
      acc[1][0]=fmaf(av.y,wv.x,acc[1][0]); acc[1][1]=fmaf(av.y,wv.y,acc[1][1]);
      acc[1][2]=fmaf(av.y,wv.z,acc[1][2]); acc[1][3]=fmaf(av.y,wv.w,acc[1][3]);
      acc[2][0]=fmaf(av.z,wv.x,acc[2][0]); acc[2][1]=fmaf(av.z,wv.y,acc[2][1]);
      acc[2][2]=fmaf(av.z,wv.z,acc[2][2]); acc[2][3]=fmaf(av.z,wv.w,acc[2][3]);
      acc[3][0]=fmaf(av.w,wv.x,acc[3][0]); acc[3][1]=fmaf(av.w,wv.y,acc[3][1]);
      acc[3][2]=fmaf(av.w,wv.z,acc[3][2]); acc[3][3]=fmaf(av.w,wv.w,acc[3][3]);
    }
  }
  float b0v = bias[nt+tn+0], b1v = bias[nt+tn+1], b2v = bias[nt+tn+2], b3v = bias[nt+tn+3];
  #pragma unroll
  for (int i=0;i<4;i++){
    float4 o;
    o.x = acc[i][0] + b0v; o.y = acc[i][1] + b1v;
    o.z = acc[i][2] + b2v; o.w = acc[i][3] + b3v;
    *(float4*)(C + (size_t)(mt + tm + i)*Hz + nt + tn) = o;
  }
}

// exact r8 logit chain: p = sum over 4 chunks of fma(v, tanh(q+x), p), seq.
__device__ __forceinline__ float logit_chain(
    const float4& x0, const float4& x1, const float4& x2, const float4& x3,
    const float4& q0, const float4& q1, const float4& q2, const float4& q3,
    const float4& v0, const float4& v1, const float4& v2, const float4& v3)
{
  float p = 0.f;
  p = fmaf(v0.x, tanhf(q0.x + x0.x), p); p = fmaf(v0.y, tanhf(q0.y + x0.y), p);
  p = fmaf(v0.z, tanhf(q0.z + x0.z), p); p = fmaf(v0.w, tanhf(q0.w + x0.w), p);
  p = fmaf(v1.x, tanhf(q1.x + x1.x), p); p = fmaf(v1.y, tanhf(q1.y + x1.y), p);
  p = fmaf(v1.z, tanhf(q1.z + x1.z), p); p = fmaf(v1.w, tanhf(q1.w + x1.w), p);
  p = fmaf(v2.x, tanhf(q2.x + x2.x), p); p = fmaf(v2.y, tanhf(q2.y + x2.y), p);
  p = fmaf(v2.z, tanhf(q2.z + x2.z), p); p = fmaf(v2.w, tanhf(q2.w + x2.w), p);
  p = fmaf(v3.x, tanhf(q3.x + x3.x), p); p = fmaf(v3.y, tanhf(q3.y + x3.y), p);
  p = fmaf(v3.z, tanhf(q3.z + x3.z), p); p = fmaf(v3.w, tanhf(q3.w + x3.w), p);
  return p;
}

// ---------------------------------------------------------------------------
// Fused attention step: 512 thr = 16 groups x 32 lanes. q/V hoisted to regs
// (one conflicted LDS read per phase instead of per row); 2-row pairing.
// Online-update ORDER preserved -> bit-identical to r8.
// ---------------------------------------------------------------------------
__global__ __launch_bounds__(512) void attn_step(
    const float* __restrict__ gl_Wq, const float* __restrict__ gl_bq,
    const float* __restrict__ gl_V,
    const float* __restrict__ pt_Wq, const float* __restrict__ pt_bq,
    const float* __restrict__ pt_V,
    int t, int hsel2, float* __restrict__ out)
{
  int b = blockIdx.x, tid = threadIdx.x;
  int wave = tid >> 6, lane64 = tid & 63;
  int g = tid >> 5, lane = tid & 31;

  __shared__ __align__(16) float hq[Hz];
  __shared__ __align__(16) float q2s[Hz];
  __shared__ __align__(16) float qgs[Hz];
  __shared__ __align__(16) float qps[Hz];
  __shared__ __align__(16) float vgl[Hz];
  __shared__ __align__(16) float vpt[Hz];
  __shared__ float part[16][513];
  __shared__ float m_arr[16];
  __shared__ float l_arr[16];
  __shared__ int   rlist[16][16];
  __shared__ float slog[Sz];
  __shared__ float redy[8]; __shared__ int redi[8];
  __shared__ float redm[8]; __shared__ float redsum[8];

  hq[tid]  = g_h[(size_t)hsel2*BH + (size_t)b*Hz + tid];
  vgl[tid] = gl_V[tid];
  vpt[tid] = pt_V[tid];
  __syncthreads();

  const unsigned char* mrow = g_mask + b*Sz;

  // ---- compacted row list per group
  int cnt;
  {
    bool un = (lane < 16) ? (mrow[g*16 + lane] == 0) : false;
    unsigned long long bal = __ballot(un);
    unsigned m16 = (unsigned)((g & 1) ? (bal >> 32) : bal) & 0xFFFFu;
    cnt = __popc(m16);
    if (lane < 16){
      if (un){
        int rank = __popc(m16 & ((1u << lane) - 1u));
        rlist[g][rank] = g*16 + lane;
      } else {
        slog[g*16 + lane] = NEGV;
      }
    }
  }

  // ---- q2 = gl_Wq @ h + gl_bq (unroll 2) — r8 verbatim
  {
    float hv[8];
    #pragma unroll
    for (int i=0;i<8;i++) hv[i] = hq[lane64*8 + i];
    for (int jj=0;jj<64;jj+=2){
      int j0 = wave*64 + jj;
      const float* wr0 = gl_Wq + (size_t)j0*Hz + lane64*8;
      const float* wr1 = wr0 + Hz;
      float4 A0 = *(const float4*)wr0, A1 = *(const float4*)(wr0+4);
      float4 B0 = *(const float4*)wr1, B1 = *(const float4*)(wr1+4);
      float p0 = 0.f, p1 = 0.f;
      p0 = fmaf(hv[0], A0.x, p0); p0 = fmaf(hv[1], A0.y, p0);
      p0 = fmaf(hv[2], A0.z, p0); p0 = fmaf(hv[3], A0.w, p0);
      p0 = fmaf(hv[4], A1.x, p0); p0 = fmaf(hv[5], A1.y, p0);
      p0 = fmaf(hv[6], A1.z, p0); p0 = fmaf(hv[7], A1.w, p0);
      p1 = fmaf(hv[0], B0.x, p1); p1 = fmaf(hv[1], B0.y, p1);
      p1 = fmaf(hv[2], B0.z, p1); p1 = fmaf(hv[3], B0.w, p1);
      p1 = fmaf(hv[4], B1.x, p1); p1 = fmaf(hv[5], B1.y, p1);
      p1 = fmaf(hv[6], B1.z, p1); p1 = fmaf(hv[7], B1.w, p1);
      #pragma unroll
      for (int off=32; off; off>>=1) p0 += __shfl_xor(p0, off);
      #pragma unroll
      for (int off=32; off; off>>=1) p1 += __shfl_xor(p1, off);
      if (lane64 == 0){ q2s[j0] = p0 + gl_bq[j0]; q2s[j0+1] = p1 + gl_bq[j0+1]; }
    }
  }
  __syncthreads();

  // ---- glimpse: online softmax, paired rows, q/V in registers
  const float* glbase = g_glref + (size_t)b*Sz*Hz;
  {
    // hoist q2s and vgl fragments (single conflicted read per phase)
    float4 q0 = *(const float4*)&q2s[lane*4];
    float4 q1 = *(const float4*)&q2s[(lane+32)*4];
    float4 q2 = *(const float4*)&q2s[(lane+64)*4];
    float4 q3 = *(const float4*)&q2s[(lane+96)*4];
    float4 v0 = *(const float4*)&vgl[lane*4];
    float4 v1 = *(const float4*)&vgl[(lane+32)*4];
    float4 v2 = *(const float4*)&vgl[(lane+64)*4];
    float4 v3 = *(const float4*)&vgl[(lane+96)*4];

    float m_g = -INFINITY, l_g = 0.f;
    float4 racc[4];
    { float4 z = {0.f,0.f,0.f,0.f}; racc[0]=z; racc[1]=z; racc[2]=z; racc[3]=z; }

    float4 xa0, xa1, xa2, xa3, xb0, xb1, xb2, xb3;
    if (cnt > 0){
      const float4* rp = (const float4*)(glbase + (size_t)rlist[g][0]*Hz);
      xa0 = rp[lane]; xa1 = rp[lane+32]; xa2 = rp[lane+64]; xa3 = rp[lane+96];
    }
    if (cnt > 1){
      const float4* rp = (const float4*)(glbase + (size_t)rlist[g][1]*Hz);
      xb0 = rp[lane]; xb1 = rp[lane+32]; xb2 = rp[lane+64]; xb3 = rp[lane+96];
    }

    for (int i = 0; i < cnt; i += 2){
      bool has2 = (i + 1 < cnt);
      float4 ya0=xa0, ya1=xa1, ya2=xa2, ya3=xa3;
      float4 yb0=xb0, yb1=xb1, yb2=xb2, yb3=xb3;
      if (i + 2 < cnt){
        const float4* rp = (const float4*)(glbase + (size_t)rlist[g][i+2]*Hz);
        xa0 = rp[lane]; xa1 = rp[lane+32]; xa2 = rp[lane+64]; xa3 = rp[lane+96];
      }
      if (i + 3 < cnt){
        const float4* rp = (const float4*)(glbase + (size_t)rlist[g][i+3]*Hz);
        xb0 = rp[lane]; xb1 = rp[lane+32]; xb2 = rp[lane+64]; xb3 = rp[lane+96];
      }
      float pa = logit_chain(ya0,ya1,ya2,ya3, q0,q1,q2,q3, v0,v1,v2,v3);
      float pb = has2 ? logit_chain(yb0,yb1,yb2,yb3, q0,q1,q2,q3, v0,v1,v2,v3) : 0.f;
      #pragma unroll
      for (int off=16; off; off>>=1){
        pa += __shfl_xor(pa, off, 32);
        pb += __shfl_xor(pb, off, 32);
      }
      // online update: row i, then row i+1 (same order as r8)
      {
        float lgv = pa;
        if (lgv > m_g){
          float r_ = expf(m_g - lgv);
          l_g *= r_;
          racc[0].x*=r_; racc[0].y*=r_; racc[0].z*=r_; racc[0].w*=r_;
          racc[1].x*=r_; racc[1].y*=r_; racc[1].z*=r_; racc[1].w*=r_;
          racc[2].x*=r_; racc[2].y*=r_; racc[2].z*=r_; racc[2].w*=r_;
          racc[3].x*=r_; racc[3].y*=r_; racc[3].z*=r_; racc[3].w*=r_;
          m_g = lgv;
        }
        float pr = expf(lgv - m_g);
        l_g += pr;
        racc[0].x=fmaf(pr,ya0.x,racc[0].x); racc[0].y=fmaf(pr,ya0.y,racc[0].y);
        racc[0].z=fmaf(pr,ya0.z,racc[0].z); racc[0].w=fmaf(pr,ya0.w,racc[0].w);
        racc[1].x=fmaf(pr,ya1.x,racc[1].x); racc[1].y=fmaf(pr,ya1.y,racc[1].y);
        racc[1].z=fmaf(pr,ya1.z,racc[1].z); racc[1].w=fmaf(pr,ya1.w,racc[1].w);
        racc[2].x=fmaf(pr,ya2.x,racc[2].x); racc[2].y=fmaf(pr,ya2.y,racc[2].y);
        racc[2].z=fmaf(pr,ya2.z,racc[2].z); racc[2].w=fmaf(pr,ya2.w,racc[2].w);
        racc[3].x=fmaf(pr,ya3.x,racc[3].x); racc[3].y=fmaf(pr,ya3.y,racc[3].y);
        racc[3].z=fmaf(pr,ya3.z,racc[3].z); racc[3].w=fmaf(pr,ya3.w,racc[3].w);
      }
      if (has2){
        float lgv = pb;
        if (lgv > m_g){
          float r_ = expf(m_g - lgv);
          l_g *= r_;
          racc[0].x*=r_; racc[0].y*=r_; racc[0].z*=r_; racc[0].w*=r_;
          racc[1].x*=r_; racc[1].y*=r_; racc[1].z*=r_; racc[1].w*=r_;
          racc[2].x*=r_; racc[2].y*=r_; racc[2].z*=r_; racc[2].w*=r_;
          racc[3].x*=r_; racc[3].y*=r_; racc[3].z*=r_; racc[3].w*=r_;
          m_g = lgv;
        }
        float pr = expf(lgv - m_g);
        l_g += pr;
        racc[0].x=fmaf(pr,yb0.x,racc[0].x); racc[0].y=fmaf(pr,yb0.y,racc[0].y);
        racc[0].z=fmaf(pr,yb0.z,racc[0].z); racc[0].w=fmaf(pr,yb0.w,racc[0].w);
        racc[1].x=fmaf(pr,yb1.x,racc[1].x); racc[1].y=fmaf(pr,yb1.y,racc[1].y);
        racc[1].z=fmaf(pr,yb1.z,racc[1].z); racc[1].w=fmaf(pr,yb1.w,racc[1].w);
        racc[2].x=fmaf(pr,yb2.x,racc[2].x); racc[2].y=fmaf(pr,yb2.y,racc[2].y);
        racc[2].z=fmaf(pr,yb2.z,racc[2].z); racc[2].w=fmaf(pr,yb2.w,racc[2].w);
        racc[3].x=fmaf(pr,yb3.x,racc[3].x); racc[3].y=fmaf(pr,yb3.y,racc[3].y);
        racc[3].z=fmaf(pr,yb3.z,racc[3].z); racc[3].w=fmaf(pr,yb3.w,racc[3].w);
      }
    }
    if (lane == 0){ m_arr[g] = m_g; l_arr[g] = l_g; }
    part[g][4*lane+  0] = racc[0].x; part[g][4*lane+  1] = racc[0].y;
    part[g][4*lane+  2] = racc[0].z; part[g][4*lane+  3] = racc[0].w;
    part[g][4*lane+128] = racc[1].x; part[g][4*lane+129] = racc[1].y;
    part[g][4*lane+130] = racc[1].z; part[g][4*lane+131] = racc[1].w;
    part[g][4*lane+256] = racc[2].x; part[g][4*lane+257] = racc[2].y;
    part[g][4*lane+258] = racc[2].z; part[g][4*lane+259] = racc[2].w;
    part[g][4*lane+384] = racc[3].x; part[g][4*lane+385] = racc[3].y;
    part[g][4*lane+386] = racc[3].z; part[g][4*lane+387] = racc[3].w;
  }
  __syncthreads();

  // ---- merge group partials -> qg (r8 verbatim)
  {
    float M = m_arr[0];
    #pragma unroll
    for (int gg=1; gg<16; gg++) M = fmaxf(M, m_arr[gg]);
    float num = 0.f, den = 0.f;
    #pragma unroll
    for (int gg=0; gg<16; gg++){
      float w = expf(m_arr[gg] - M);
      num = fmaf(w, part[gg][tid], num);
      den = fmaf(w, l_arr[gg], den);
    }
    qgs[tid] = num / den;
  }
  __syncthreads();

  // ---- qpt = pt_Wq @ qg + pt_bq (unroll 2) — r8 verbatim
  {
    float qv[8];
    #pragma unroll
    for (int i=0;i<8;i++) qv[i] = qgs[lane64*8 + i];
    for (int jj=0;jj<64;jj+=2){
      int j0 = wave*64 + jj;
      const float* wr0 = pt_Wq + (size_t)j0*Hz + lane64*8;
      const float* wr1 = wr0 + Hz;
      float4 A0 = *(const float4*)wr0, A1 = *(const float4*)(wr0+4);
      float4 B0 = *(const float4*)wr1, B1 = *(const float4*)(wr1+4);
      float p0 = 0.f, p1 = 0.f;
      p0 = fmaf(qv[0], A0.x, p0); p0 = fmaf(qv[1], A0.y, p0);
      p0 = fmaf(qv[2], A0.z, p0); p0 = fmaf(qv[3], A0.w, p0);
      p0 = fmaf(qv[4], A1.x, p0); p0 = fmaf(qv[5], A1.y, p0);
      p0 = fmaf(qv[6], A1.z, p0); p0 = fmaf(qv[7], A1.w, p0);
      p1 = fmaf(qv[0], B0.x, p1); p1 = fmaf(qv[1], B0.y, p1);
      p1 = fmaf(qv[2], B0.z, p1); p1 = fmaf(qv[3], B0.w, p1);
      p1 = fmaf(qv[4], B1.x, p1); p1 = fmaf(qv[5], B1.y, p1);
      p1 = fmaf(qv[6], B1.z, p1); p1 = fmaf(qv[7], B1.w, p1);
      #pragma unroll
      for (int off=32; off; off>>=1) p0 += __shfl_xor(p0, off);
      #pragma unroll
      for (int off=32; off; off>>=1) p1 += __shfl_xor(p1, off);
      if (lane64 == 0){ qps[j0] = p0 + pt_bq[j0]; qps[j0+1] = p1 + pt_bq[j0+1]; }
    }
  }
  __syncthreads();

  // ---- pointer pass: paired rows, q/V in registers
  const float* ptbase = g_ptref + (size_t)b*Sz*Hz;
  {
    float4 q0 = *(const float4*)&qps[lane*4];
    float4 q1 = *(const float4*)&qps[(lane+32)*4];
    float4 q2 = *(const float4*)&qps[(lane+64)*4];
    float4 q3 = *(const float4*)&qps[(lane+96)*4];
    float4 v0 = *(const float4*)&vpt[lane*4];
    float4 v1 = *(const float4*)&vpt[(lane+32)*4];
    float4 v2 = *(const float4*)&vpt[(lane+64)*4];
    float4 v3 = *(const float4*)&vpt[(lane+96)*4];

    float4 xa0, xa1, xa2, xa3, xb0, xb1, xb2, xb3;
    if (cnt > 0){
      const float4* rp = (const float4*)(ptbase + (size_t)rlist[g][0]*Hz);
      xa0 = rp[lane]; xa1 = rp[lane+32]; xa2 = rp[lane+64]; xa3 = rp[lane+96];
    }
    if (cnt > 1){
      const float4* rp = (const float4*)(ptbase + (size_t)rlist[g][1]*Hz);
      xb0 = rp[lane]; xb1 = rp[lane+32]; xb2 = rp[lane+64]; xb3 = rp[lane+96];
    }
    for (int i = 0; i < cnt; i += 2){
      bool has2 = (i + 1 < cnt);
      int sa = rlist[g][i];
      int sb = has2 ? rlist[g][i+1] : 0;
      float4 ya0=xa0, ya1=xa1, ya2=xa2, ya3=xa3;
      float4 yb0=xb0, yb1=xb1, yb2=xb2, yb3=xb3;
      if (i + 2 < cnt){
        const float4* rp = (const float4*)(ptbase + (size_t)rlist[g][i+2]*Hz);
        xa0 = rp[lane]; xa1 = rp[lane+32]; xa2 = rp[lane+64]; xa3 = rp[lane+96];
      }
      if (i + 3 < cnt){
        const float4* rp = (const float4*)(ptbase + (size_t)rlist[g][i+3]*Hz);
        xb0 = rp[lane]; xb1 = rp[lane+32]; xb2 = rp[lane+64]; xb3 = rp[lane+96];
      }
      float pa = logit_chain(ya0,ya1,ya2,ya3, q0,q1,q2,q3, v0,v1,v2,v3);
      float pb = has2 ? logit_chain(yb0,yb1,yb2,yb3, q0,q1,q2,q3, v0,v1,v2,v3) : 0.f;
      #pragma unroll
      for (int off=16; off; off>>=1){
        pa += __shfl_xor(pa, off, 32);
        pb += __shfl_xor(pb, off, 32);
      }
      if (lane == 0){
        slog[sa] = 10.f * tanhf(pa);
        if (has2) slog[sb] = 10.f * tanhf(pb);
      }
    }
  }
  __syncthreads();

  // ---- Gumbel-max sample (r8 verbatim)
  float lg = NEGV, y = -INFINITY;
  if (tid < Sz){
    lg = slog[tid];
    unsigned bits = rng_bits(g_keys[2*t], g_keys[2*t+1], (unsigned)(b*Sz + tid));
    float u = __uint_as_float((bits >> 9) | 0x3f800000u) - 1.f;
    float gum = -logf(-logf(u + 1e-10f) + 1e-10f);
    y = lg + gum;
  }
  float by = y; int bi = tid; float bm = lg;
  #pragma unroll
  for (int off=32; off; off>>=1){
    float oy = __shfl_xor(by, off);
    int   oi = __shfl_xor(bi, off);
    float om = __shfl_xor(bm, off);
    if (oy > by || (oy == by && oi < bi)){ by = oy; bi = oi; }
    bm = fmaxf(bm, om);
  }
  if (lane64 == 0){ redy[wave] = by; redi[wave] = bi; redm[wave] = bm; }
  __syncthreads();
  float fy = redy[0]; int fi = redi[0]; float fm = redm[0];
  #pragma unroll
  for (int w=1; w<8; w++){
    if (redy[w] > fy || (redy[w] == fy && redi[w] < fi)){ fy = redy[w]; fi = redi[w]; }
    fm = fmaxf(fm, redm[w]);
  }
  int ptr = fi;

  float pe = (tid < Sz) ? expf(lg - fm) : 0.f;
  #pragma unroll
  for (int off=32; off; off>>=1) pe += __shfl_xor(pe, off);
  if (lane64 == 0) redsum[wave] = pe;
  __syncthreads();
  if (tid == 0){
    float den = ((redsum[0]+redsum[1]) + (redsum[2]+redsum[3]))
              + ((redsum[4]+redsum[5]) + (redsum[6]+redsum[7]));
    float logp = slog[ptr] - fm - logf(den);
    out[(size_t)b*Sz + t] = (float)ptr;
    out[(size_t)Bz*Sz + (size_t)b*Sz + t] = logp;
    g_mask[b*Sz + ptr] = 1;
    g_ptrbuf[b] = ptr;
  }
}

// ---------------------------------------------------------------------------
extern "C" void kernel_launch(void* const* d_in, const int* in_sizes, int n_in,
                              void* d_out, int out_size, void* d_ws, size_t ws_size,
                              hipStream_t stream){
  (void)in_sizes; (void)n_in; (void)out_size; (void)d_ws; (void)ws_size;
  const float* embedding = (const float*)d_in[0];
  const float* enc_Wih = (const float*)d_in[1];
  const float* enc_Whh = (const float*)d_in[2];
  const float* enc_b   = (const float*)d_in[3];
  const float* dec_Wih = (const float*)d_in[4];
  const float* dec_Whh = (const float*)d_in[5];
  const float* dec_b   = (const float*)d_in[6];
  const float* pt_Wq   = (const float*)d_in[7];
  const float* pt_bq   = (const float*)d_in[8];
  const float* pt_Wref = (const float*)d_in[9];
  const float* pt_bref = (const float*)d_in[10];
  const float* pt_V    = (const float*)d_in[11];
  const float* gl_Wq   = (const float*)d_in[12];
  const float* gl_bq   = (const float*)d_in[13];
  const float* gl_Wref = (const float*)d_in[14];
  const float* gl_bref = (const float*)d_in[15];
  const float* gl_V    = (const float*)d_in[16];
  const float* dec_start = (const float*)d_in[17];
  const int*   inputs  = (const int*)d_in[18];
  float* out = (float*)d_out;

  init_kernel<<<512, 256, 0, stream>>>();
  xproj_kernel<<<dim3(256,8), 256, 0, stream>>>(enc_Wih, enc_b, embedding, dec_start, 0);
  xproj_kernel<<<dim3(257,8), 256, 0, stream>>>(dec_Wih, dec_b, embedding, dec_start, 1);

  // ---- encoder ----
  for (int t = 0; t < Sz; t++){
    lstm_step<<<dim3(16,32), 256, 0, stream>>>(enc_Whh, inputs, t, 0, t & 1);
  }
  // ---- ref projections ----
  gemm_ref<<<dim3(1024,8), 256, 0, stream>>>(gl_Wref, gl_bref, 1);
  gemm_ref<<<dim3(1024,8), 256, 0, stream>>>(pt_Wref, pt_bref, 2);

  // ---- decoder ----
  for (int t = 0; t < Sz; t++){
    lstm_step<<<dim3(16,32), 256, 0, stream>>>(dec_Whh, inputs, t, 1, t & 1);
    attn_step<<<Bz, 512, 0, stream>>>(gl_Wq, gl_bq, gl_V,
        pt_Wq, pt_bq, pt_V, t, (t+1) & 1, out);
  }
}